// Round 2
// baseline (441.277 us; speedup 1.0000x reference)
//
#include <hip/hip_runtime.h>
#include <hip/hip_bf16.h>

typedef __attribute__((ext_vector_type(4))) float floatx4;
typedef __attribute__((ext_vector_type(2))) float floatx2;
typedef __attribute__((ext_vector_type(8))) __bf16 bf16x8;
typedef __attribute__((ext_vector_type(8))) unsigned short ushortx8;

__device__ __forceinline__ unsigned short f2bf(float x) {
    union { float f; unsigned u; } v; v.f = x;
    unsigned r = v.u + 0x7fffu + ((v.u >> 16) & 1u);
    return (unsigned short)(r >> 16);
}

__device__ __forceinline__ bf16x8 as_bf(ushortx8 v) {
    union { ushortx8 u; bf16x8 b; } x; x.u = v; return x.b;
}

__device__ __forceinline__ bf16x8 cvt8(floatx4 lo, floatx4 hi) {
    union { bf16x8 v; __hip_bfloat162 h[4]; } u;
    float2 p;
    p.x = lo.x; p.y = lo.y; u.h[0] = __float22bfloat162_rn(p);
    p.x = lo.z; p.y = lo.w; u.h[1] = __float22bfloat162_rn(p);
    p.x = hi.x; p.y = hi.y; u.h[2] = __float22bfloat162_rn(p);
    p.x = hi.z; p.y = hi.w; u.h[3] = __float22bfloat162_rn(p);
    return u.v;
}

// ============ K1: U0 = Wf[:, :256]@OP, U1 = Wf[:, 256:]@OP,
//                  Vimg = Wv@W_img, Vtxt = Wv@W_text, + matvecs (c, vb_img, vb_txt)
// bid 0-15: U0 tiles (4x4 of 64x64) | 16-31: U1 | 32-63: Vimg (4x8) | 64-95: Vtxt | 96: matvecs
__global__ void k1_tree(const float* __restrict__ W_fuse, const float* __restrict__ OP,
                        const float* __restrict__ ipw, const float* __restrict__ ipb,
                        const float* __restrict__ W_img, const float* __restrict__ W_text,
                        const float* __restrict__ opb, const float* __restrict__ b_img,
                        const float* __restrict__ b_text,
                        float* __restrict__ U0, float* __restrict__ U1,
                        float* __restrict__ Vimg, float* __restrict__ Vtxt,
                        float* __restrict__ vb_img, float* __restrict__ vb_txt,
                        float* __restrict__ cvec) {
    const int bid = blockIdx.x;
    const int t = threadIdx.x;
    const float* Wv = ipw + 512 * 256;
    if (bid == 96) {
        if (t < 256) {
            float a0 = opb[t], a1 = 0.f, a2 = 0.f;
            const float* oprow = OP + t * 256;
            const float* wvrow = Wv + t * 256;
            #pragma unroll 4
            for (int k = 0; k < 256; ++k) {
                a0 = fmaf(oprow[k], ipb[512 + k], a0);
                a1 = fmaf(wvrow[k], b_img[k], a1);
                a2 = fmaf(wvrow[k], b_text[k], a2);
            }
            cvec[t] = a0; vb_img[t] = a1; vb_txt[t] = a2;
        }
        return;
    }
    const float *A, *B; float* C; int lda, ldb, ldc, aoff, tm, tn;
    if (bid < 32) {
        int h = bid >> 4, tt = bid & 15;
        A = W_fuse; lda = 512; aoff = h * 256;
        B = OP; ldb = 256; C = h ? U1 : U0; ldc = 256;
        tm = tt >> 2; tn = tt & 3;
    } else {
        int b2 = bid - 32; int h = b2 >> 5; int tt = b2 & 31;
        A = Wv; lda = 256; aoff = 0;
        B = h ? W_text : W_img; ldb = 512; C = h ? Vtxt : Vimg; ldc = 512;
        tm = tt >> 3; tn = tt & 7;
    }
    __shared__ float As[16][68];   // transposed A-tile: As[k][row]
    __shared__ float Bs[16][68];
    const int arow = t >> 3, ak = (t & 7) * 2;        // 512 thr: 64 rows x 8 float2
    const int brow = t >> 5, bc = (t & 31) * 2;       // 16 rows x 32 float2
    const int ty = t >> 4, tx = t & 15;               // compute: rows ty*2+{0,1}, cols tx*4
    float acc[2][4] = {};
    for (int k0 = 0; k0 < 256; k0 += 16) {
        floatx2 av = *(const floatx2*)(A + (size_t)(tm * 64 + arow) * lda + aoff + k0 + ak);
        floatx2 bv = *(const floatx2*)(B + (size_t)(k0 + brow) * ldb + tn * 64 + bc);
        __syncthreads();
        As[ak + 0][arow] = av.x;
        As[ak + 1][arow] = av.y;
        *(floatx2*)&Bs[brow][bc] = bv;
        __syncthreads();
        #pragma unroll
        for (int kk = 0; kk < 16; ++kk) {
            floatx2 a = *(const floatx2*)&As[kk][ty * 2];
            floatx4 b = *(const floatx4*)&Bs[kk][tx * 4];
            acc[0][0] = fmaf(a.x, b.x, acc[0][0]); acc[0][1] = fmaf(a.x, b.y, acc[0][1]);
            acc[0][2] = fmaf(a.x, b.z, acc[0][2]); acc[0][3] = fmaf(a.x, b.w, acc[0][3]);
            acc[1][0] = fmaf(a.y, b.x, acc[1][0]); acc[1][1] = fmaf(a.y, b.y, acc[1][1]);
            acc[1][2] = fmaf(a.y, b.z, acc[1][2]); acc[1][3] = fmaf(a.y, b.w, acc[1][3]);
        }
    }
    #pragma unroll
    for (int i = 0; i < 2; ++i) {
        floatx4 o; o.x = acc[i][0]; o.y = acc[i][1]; o.z = acc[i][2]; o.w = acc[i][3];
        *(floatx4*)(C + (size_t)(tm * 64 + ty * 2 + i) * ldc + tn * 64 + tx * 4) = o;
    }
}

// ============ K2: A_half = U_h @ V_h -> Wt (bf16 B-fragment layout); bid 64: b_total
__global__ void k2_A(const float* __restrict__ U0, const float* __restrict__ U1,
                     const float* __restrict__ Vimg, const float* __restrict__ Vtxt,
                     const float* __restrict__ W_fuse, const float* __restrict__ b_fuse,
                     const float* __restrict__ vb_img, const float* __restrict__ vb_txt,
                     const float* __restrict__ cvec,
                     unsigned short* __restrict__ Wt, float* __restrict__ b_total) {
    const int bid = blockIdx.x;
    const int t = threadIdx.x;
    if (bid == 64) {
        if (t < 256) {
            float acc = b_fuse[t];
            const float* u0 = U0 + t * 256;
            const float* u1 = U1 + t * 256;
            const float* wf = W_fuse + t * 512;
            #pragma unroll 4
            for (int j = 0; j < 256; ++j) {
                acc = fmaf(u0[j], vb_img[j], acc);
                acc = fmaf(u1[j], vb_txt[j], acc);
                acc = fmaf(wf[j] + wf[j + 256], cvec[j], acc);
            }
            b_total[t] = acc;
        }
        return;
    }
    const int h = bid >> 5, tt = bid & 31;
    const float* A = h ? U1 : U0;     // [256 x 256]
    const float* B = h ? Vtxt : Vimg; // [256 x 512]
    const int tm = tt >> 3, tn = tt & 7;
    __shared__ float As[16][68];
    __shared__ float Bs[16][68];
    const int arow = t >> 3, ak = (t & 7) * 2;
    const int brow = t >> 5, bc = (t & 31) * 2;
    const int n_l = t >> 3, oct = t & 7;     // thread: 1 row n, 8 consecutive kk
    float acc[8] = {};
    for (int k0 = 0; k0 < 256; k0 += 16) {
        floatx2 av = *(const floatx2*)(A + (size_t)(tm * 64 + arow) * 256 + k0 + ak);
        floatx2 bv = *(const floatx2*)(B + (size_t)(k0 + brow) * 512 + tn * 64 + bc);
        __syncthreads();
        As[ak + 0][arow] = av.x;
        As[ak + 1][arow] = av.y;
        *(floatx2*)&Bs[brow][bc] = bv;
        __syncthreads();
        #pragma unroll
        for (int kk = 0; kk < 16; ++kk) {
            float u = As[kk][n_l];
            floatx4 v0 = *(const floatx4*)&Bs[kk][oct * 8];
            floatx4 v1 = *(const floatx4*)&Bs[kk][oct * 8 + 4];
            acc[0] = fmaf(u, v0.x, acc[0]); acc[1] = fmaf(u, v0.y, acc[1]);
            acc[2] = fmaf(u, v0.z, acc[2]); acc[3] = fmaf(u, v0.w, acc[3]);
            acc[4] = fmaf(u, v1.x, acc[4]); acc[5] = fmaf(u, v1.y, acc[5]);
            acc[6] = fmaf(u, v1.z, acc[6]); acc[7] = fmaf(u, v1.w, acc[7]);
        }
    }
    // Wt layout (verified round 1): ((nt*32 + kq)*64 + q*16 + nl)*8 + jj
    const int n = tm * 64 + n_l;
    const int kg = h * 512 + tn * 64 + oct * 8;
    const int kq = kg >> 5, q = (kg >> 3) & 3;
    const int nt = n >> 4, nl = n & 15;
    union { ushortx8 v; unsigned short s[8]; } o;
    #pragma unroll
    for (int j = 0; j < 8; ++j) o.s[j] = f2bf(acc[j]);
    *(ushortx8*)&Wt[(size_t)((nt * 32 + kq) * 64 + q * 16 + nl) * 8] = o.v;
}

// ============ Main: out = relu([img|txt] @ Wt^T + b_total) — barrier-free, no LDS
__global__ __launch_bounds__(256, 2)
void fused_gemm(const float* __restrict__ Ximg, const float* __restrict__ Xtxt,
                const unsigned short* __restrict__ Wt,
                const float* __restrict__ b_total, float* __restrict__ out) {
    const int bid = blockIdx.x;
    const int rowtile = bid >> 1, cb = bid & 1;
    const int t = threadIdx.x, lane = t & 63, w = t >> 6;
    const int ml = lane & 15, q = lane >> 4;
    const size_t rowbase = (size_t)rowtile * 128 + w * 32;
    const size_t roff0 = (rowbase + ml) * 512 + q * 8;   // A-frag: row=ml, k=q*8+j
    const size_t roff1 = roff0 + (size_t)16 * 512;
    const unsigned short* wbase = Wt + ((size_t)(cb * 8) * 32) * 512 + lane * 8;

    floatx4 acc[2][8];
    #pragma unroll
    for (int mi = 0; mi < 2; ++mi)
        #pragma unroll
        for (int ni = 0; ni < 8; ++ni) acc[mi][ni] = (floatx4){0.f, 0.f, 0.f, 0.f};

    floatx4 aA[2][2], aB[2][2];

    auto loadA = [&](int idx, floatx4 (&dst)[2][2]) {
        const float* X = (idx < 16) ? Ximg : Xtxt;
        const size_t ko = (size_t)(idx & 15) * 32;
        dst[0][0] = *(const floatx4*)(X + roff0 + ko);
        dst[0][1] = *(const floatx4*)(X + roff0 + ko + 4);
        dst[1][0] = *(const floatx4*)(X + roff1 + ko);
        dst[1][1] = *(const floatx4*)(X + roff1 + ko + 4);
    };
    auto loadB = [&](int kq, ushortx8 (&bf)[8]) {
        const unsigned short* p = wbase + (size_t)kq * 512;
        #pragma unroll
        for (int ni = 0; ni < 8; ++ni) bf[ni] = *(const ushortx8*)(p + (size_t)ni * 32 * 512);
    };
    auto docompute = [&](floatx4 (&af32)[2][2], ushortx8 (&bf)[8]) {
        bf16x8 af[2];
        #pragma unroll
        for (int mi = 0; mi < 2; ++mi) af[mi] = cvt8(af32[mi][0], af32[mi][1]);
        #pragma unroll
        for (int mi = 0; mi < 2; ++mi)
            #pragma unroll
            for (int ni = 0; ni < 8; ++ni)
                acc[mi][ni] = __builtin_amdgcn_mfma_f32_16x16x32_bf16(af[mi], as_bf(bf[ni]), acc[mi][ni], 0, 0, 0);
    };

    loadA(0, aA);
    #pragma unroll 2
    for (int kq = 0; kq < 32; kq += 2) {
        ushortx8 b0[8];
        loadB(kq, b0);          // B(kq) issued first …
        loadA(kq + 1, aB);      // … then A(kq+1): MFMA's vmcnt wait leaves A-prefetch in flight
        docompute(aA, b0);
        ushortx8 b1[8];
        loadB(kq + 1, b1);
        loadA(kq + 2, aA);      // kq==30 -> idx 32 reads Xtxt[rows][0..7]: valid, discarded
        docompute(aB, b1);
    }

    const int colbase = cb * 128;
    #pragma unroll
    for (int ni = 0; ni < 8; ++ni) {
        const int col = colbase + ni * 16 + ml;
        const float bias = b_total[col];
        #pragma unroll
        for (int mi = 0; mi < 2; ++mi) {
            const size_t r0 = rowbase + mi * 16 + q * 4;
            #pragma unroll
            for (int e = 0; e < 4; ++e) {
                float v = acc[mi][ni][e] + bias;
                out[(r0 + e) * 256 + col] = fmaxf(v, 0.f);
            }
        }
    }
}

extern "C" void kernel_launch(void* const* d_in, const int* in_sizes, int n_in,
                              void* d_out, int out_size, void* d_ws, size_t ws_size,
                              hipStream_t stream) {
    const float* text       = (const float*)d_in[0];
    const float* image      = (const float*)d_in[1];
    const float* W_text     = (const float*)d_in[2];
    const float* b_text     = (const float*)d_in[3];
    const float* W_img      = (const float*)d_in[4];
    const float* b_img      = (const float*)d_in[5];
    const float* in_proj_w  = (const float*)d_in[6];
    const float* in_proj_b  = (const float*)d_in[7];
    const float* out_proj_w = (const float*)d_in[8];
    const float* out_proj_b = (const float*)d_in[9];
    const float* W_fuse     = (const float*)d_in[10];
    const float* b_fuse     = (const float*)d_in[11];
    float* out = (float*)d_out;

    float* ws      = (float*)d_ws;
    float* U0      = ws;                 // 65536
    float* U1      = ws + 65536;         // 65536
    float* Vimg    = ws + 131072;        // 131072
    float* Vtxt    = ws + 262144;        // 131072
    float* vb_img  = ws + 393216;        // 256
    float* vb_txt  = ws + 393472;        // 256
    float* cvec    = ws + 393728;        // 256
    float* b_total = ws + 393984;        // 256
    unsigned short* Wt = (unsigned short*)(ws + 394240);  // 262144 bf16

    k1_tree<<<dim3(97), dim3(512), 0, stream>>>(W_fuse, out_proj_w, in_proj_w, in_proj_b,
                                                W_img, W_text, out_proj_b, b_img, b_text,
                                                U0, U1, Vimg, Vtxt, vb_img, vb_txt, cvec);
    k2_A<<<dim3(65), dim3(512), 0, stream>>>(U0, U1, Vimg, Vtxt, W_fuse, b_fuse,
                                             vb_img, vb_txt, cvec, Wt, b_total);
    fused_gemm<<<dim3(1024), dim3(256), 0, stream>>>(image, text, Wt, b_total, out);
}

// Round 3
// 396.776 us; speedup vs baseline: 1.1122x; 1.1122x over previous
//
#include <hip/hip_runtime.h>
#include <hip/hip_bf16.h>

typedef __attribute__((ext_vector_type(4))) float floatx4;
typedef __attribute__((ext_vector_type(2))) float floatx2;
typedef __attribute__((ext_vector_type(8))) __bf16 bf16x8;
typedef __attribute__((ext_vector_type(8))) unsigned short ushortx8;

__device__ __forceinline__ unsigned short f2bf(float x) {
    union { float f; unsigned u; } v; v.f = x;
    unsigned r = v.u + 0x7fffu + ((v.u >> 16) & 1u);
    return (unsigned short)(r >> 16);
}

__device__ __forceinline__ bf16x8 as_bf(ushortx8 v) {
    union { ushortx8 u; bf16x8 b; } x; x.u = v; return x.b;
}

__device__ __forceinline__ bf16x8 cvt8(floatx4 lo, floatx4 hi) {
    union { bf16x8 v; __hip_bfloat162 h[4]; } u;
    float2 p;
    p.x = lo.x; p.y = lo.y; u.h[0] = __float22bfloat162_rn(p);
    p.x = lo.z; p.y = lo.w; u.h[1] = __float22bfloat162_rn(p);
    p.x = hi.x; p.y = hi.y; u.h[2] = __float22bfloat162_rn(p);
    p.x = hi.z; p.y = hi.w; u.h[3] = __float22bfloat162_rn(p);
    return u.v;
}

// ============ K1: U0 = Wf[:, :256]@OP, U1 = Wf[:, 256:]@OP,
//                  Vimg = Wv@W_img, Vtxt = Wv@W_text, + matvecs (c, vb_img, vb_txt)
__global__ void k1_tree(const float* __restrict__ W_fuse, const float* __restrict__ OP,
                        const float* __restrict__ ipw, const float* __restrict__ ipb,
                        const float* __restrict__ W_img, const float* __restrict__ W_text,
                        const float* __restrict__ opb, const float* __restrict__ b_img,
                        const float* __restrict__ b_text,
                        float* __restrict__ U0, float* __restrict__ U1,
                        float* __restrict__ Vimg, float* __restrict__ Vtxt,
                        float* __restrict__ vb_img, float* __restrict__ vb_txt,
                        float* __restrict__ cvec) {
    const int bid = blockIdx.x;
    const int t = threadIdx.x;
    const float* Wv = ipw + 512 * 256;
    if (bid == 96) {
        if (t < 256) {
            float a0 = opb[t], a1 = 0.f, a2 = 0.f;
            const float* oprow = OP + t * 256;
            const float* wvrow = Wv + t * 256;
            #pragma unroll 4
            for (int k = 0; k < 256; ++k) {
                a0 = fmaf(oprow[k], ipb[512 + k], a0);
                a1 = fmaf(wvrow[k], b_img[k], a1);
                a2 = fmaf(wvrow[k], b_text[k], a2);
            }
            cvec[t] = a0; vb_img[t] = a1; vb_txt[t] = a2;
        }
        return;
    }
    const float *A, *B; float* C; int lda, ldb, ldc, aoff, tm, tn;
    if (bid < 32) {
        int h = bid >> 4, tt = bid & 15;
        A = W_fuse; lda = 512; aoff = h * 256;
        B = OP; ldb = 256; C = h ? U1 : U0; ldc = 256;
        tm = tt >> 2; tn = tt & 3;
    } else {
        int b2 = bid - 32; int h = b2 >> 5; int tt = b2 & 31;
        A = Wv; lda = 256; aoff = 0;
        B = h ? W_text : W_img; ldb = 512; C = h ? Vtxt : Vimg; ldc = 512;
        tm = tt >> 3; tn = tt & 7;
    }
    __shared__ float As[16][68];
    __shared__ float Bs[16][68];
    const int arow = t >> 3, ak = (t & 7) * 2;
    const int brow = t >> 5, bc = (t & 31) * 2;
    const int ty = t >> 4, tx = t & 15;
    float acc[2][4] = {};
    for (int k0 = 0; k0 < 256; k0 += 16) {
        floatx2 av = *(const floatx2*)(A + (size_t)(tm * 64 + arow) * lda + aoff + k0 + ak);
        floatx2 bv = *(const floatx2*)(B + (size_t)(k0 + brow) * ldb + tn * 64 + bc);
        __syncthreads();
        As[ak + 0][arow] = av.x;
        As[ak + 1][arow] = av.y;
        *(floatx2*)&Bs[brow][bc] = bv;
        __syncthreads();
        #pragma unroll
        for (int kk = 0; kk < 16; ++kk) {
            floatx2 a = *(const floatx2*)&As[kk][ty * 2];
            floatx4 b = *(const floatx4*)&Bs[kk][tx * 4];
            acc[0][0] = fmaf(a.x, b.x, acc[0][0]); acc[0][1] = fmaf(a.x, b.y, acc[0][1]);
            acc[0][2] = fmaf(a.x, b.z, acc[0][2]); acc[0][3] = fmaf(a.x, b.w, acc[0][3]);
            acc[1][0] = fmaf(a.y, b.x, acc[1][0]); acc[1][1] = fmaf(a.y, b.y, acc[1][1]);
            acc[1][2] = fmaf(a.y, b.z, acc[1][2]); acc[1][3] = fmaf(a.y, b.w, acc[1][3]);
        }
    }
    #pragma unroll
    for (int i = 0; i < 2; ++i) {
        floatx4 o; o.x = acc[i][0]; o.y = acc[i][1]; o.z = acc[i][2]; o.w = acc[i][3];
        *(floatx4*)(C + (size_t)(tm * 64 + ty * 2 + i) * ldc + tn * 64 + tx * 4) = o;
    }
}

// ============ K2: A_half = U_h @ V_h -> Wt (bf16 B-fragment layout); bid 64: b_total
__global__ void k2_A(const float* __restrict__ U0, const float* __restrict__ U1,
                     const float* __restrict__ Vimg, const float* __restrict__ Vtxt,
                     const float* __restrict__ W_fuse, const float* __restrict__ b_fuse,
                     const float* __restrict__ vb_img, const float* __restrict__ vb_txt,
                     const float* __restrict__ cvec,
                     unsigned short* __restrict__ Wt, float* __restrict__ b_total) {
    const int bid = blockIdx.x;
    const int t = threadIdx.x;
    if (bid == 64) {
        if (t < 256) {
            float acc = b_fuse[t];
            const float* u0 = U0 + t * 256;
            const float* u1 = U1 + t * 256;
            const float* wf = W_fuse + t * 512;
            #pragma unroll 4
            for (int j = 0; j < 256; ++j) {
                acc = fmaf(u0[j], vb_img[j], acc);
                acc = fmaf(u1[j], vb_txt[j], acc);
                acc = fmaf(wf[j] + wf[j + 256], cvec[j], acc);
            }
            b_total[t] = acc;
        }
        return;
    }
    const int h = bid >> 5, tt = bid & 31;
    const float* A = h ? U1 : U0;
    const float* B = h ? Vtxt : Vimg;
    const int tm = tt >> 3, tn = tt & 7;
    __shared__ float As[16][68];
    __shared__ float Bs[16][68];
    const int arow = t >> 3, ak = (t & 7) * 2;
    const int brow = t >> 5, bc = (t & 31) * 2;
    const int n_l = t >> 3, oct = t & 7;
    float acc[8] = {};
    for (int k0 = 0; k0 < 256; k0 += 16) {
        floatx2 av = *(const floatx2*)(A + (size_t)(tm * 64 + arow) * 256 + k0 + ak);
        floatx2 bv = *(const floatx2*)(B + (size_t)(k0 + brow) * 512 + tn * 64 + bc);
        __syncthreads();
        As[ak + 0][arow] = av.x;
        As[ak + 1][arow] = av.y;
        *(floatx2*)&Bs[brow][bc] = bv;
        __syncthreads();
        #pragma unroll
        for (int kk = 0; kk < 16; ++kk) {
            float u = As[kk][n_l];
            floatx4 v0 = *(const floatx4*)&Bs[kk][oct * 8];
            floatx4 v1 = *(const floatx4*)&Bs[kk][oct * 8 + 4];
            acc[0] = fmaf(u, v0.x, acc[0]); acc[1] = fmaf(u, v0.y, acc[1]);
            acc[2] = fmaf(u, v0.z, acc[2]); acc[3] = fmaf(u, v0.w, acc[3]);
            acc[4] = fmaf(u, v1.x, acc[4]); acc[5] = fmaf(u, v1.y, acc[5]);
            acc[6] = fmaf(u, v1.z, acc[6]); acc[7] = fmaf(u, v1.w, acc[7]);
        }
    }
    const int n = tm * 64 + n_l;
    const int kg = h * 512 + tn * 64 + oct * 8;
    const int kq = kg >> 5, q = (kg >> 3) & 3;
    const int nt = n >> 4, nl = n & 15;
    union { ushortx8 v; unsigned short s[8]; } o;
    #pragma unroll
    for (int j = 0; j < 8; ++j) o.s[j] = f2bf(acc[j]);
    *(ushortx8*)&Wt[(size_t)((nt * 32 + kq) * 64 + q * 16 + nl) * 8] = o.v;
}

// ============ Main: 32 rows x 256 cols per block; async f32 staging via global_load_lds;
//              X read exactly once from HBM; B streamed from L2-resident Wt.
__global__ __launch_bounds__(256, 2)
void fused_gemm(const float* __restrict__ Ximg, const float* __restrict__ Xtxt,
                const unsigned short* __restrict__ Wt,
                const float* __restrict__ b_total, float* __restrict__ out) {
    // 2 buffers x 32 rows x 260 f32 (1040 B pitch: +16B pad to spread banks)
    __shared__ float lds[2][32 * 260];
    const int t = threadIdx.x, lane = t & 63, w = t >> 6;
    const int ml = lane & 15, q = lane >> 4;
    const size_t rowbase = (size_t)blockIdx.x * 32;

    floatx4 acc[2][4];
    #pragma unroll
    for (int mi = 0; mi < 2; ++mi)
        #pragma unroll
        for (int ni = 0; ni < 4; ++ni) acc[mi][ni] = (floatx4){0.f, 0.f, 0.f, 0.f};

    // stage step s (k-strip of 256 f32) into buffer b: one dwordx4-LDS instr per row
    auto stage = [&](int s, int b) {
        const float* X = (s < 2) ? Ximg : Xtxt;
        const int koff = (s & 1) * 256;
        #pragma unroll
        for (int i = 0; i < 8; ++i) {
            const int r = w * 8 + i;                         // wave-uniform row
            const float* gp = X + (rowbase + r) * 512 + koff + lane * 4;
            float* lp = &lds[b][r * 260];
            __builtin_amdgcn_global_load_lds(
                (const __attribute__((address_space(1))) unsigned int*)gp,
                (__attribute__((address_space(3))) unsigned int*)lp, 16, 0, 0);
        }
    };

    auto compute = [&](int s, int b) {
        #pragma unroll
        for (int kqi = 0; kqi < 8; ++kqi) {
            const int kq = s * 8 + kqi;
            bf16x8 af[2];
            #pragma unroll
            for (int mi = 0; mi < 2; ++mi) {
                const float* p = &lds[b][(mi * 16 + ml) * 260 + kqi * 32 + q * 8];
                floatx4 lo = *(const floatx4*)p;
                floatx4 hi = *(const floatx4*)(p + 4);
                af[mi] = cvt8(lo, hi);
            }
            #pragma unroll
            for (int ni = 0; ni < 4; ++ni) {
                const int nt = w * 4 + ni;
                ushortx8 bv = *(const ushortx8*)(Wt + (size_t)((nt * 32 + kq) * 64 + lane) * 8);
                #pragma unroll
                for (int mi = 0; mi < 2; ++mi)
                    acc[mi][ni] = __builtin_amdgcn_mfma_f32_16x16x32_bf16(af[mi], as_bf(bv), acc[mi][ni], 0, 0, 0);
            }
        }
    };

    stage(0, 0);
    for (int s = 0; s < 4; ++s) {
        __syncthreads();                 // drains stage(s) (vmcnt) + prior ds_reads
        if (s < 3) stage(s + 1, (s + 1) & 1);   // 32 KB burst in flight during compute+wait
        compute(s, s & 1);
    }

    // epilogue: C/D layout col=lane&15, row=q*4+e
    #pragma unroll
    for (int ni = 0; ni < 4; ++ni) {
        const int col = w * 64 + ni * 16 + ml;
        const float bias = b_total[col];
        #pragma unroll
        for (int mi = 0; mi < 2; ++mi) {
            const size_t r0 = rowbase + mi * 16 + q * 4;
            #pragma unroll
            for (int e = 0; e < 4; ++e) {
                float v = acc[mi][ni][e] + bias;
                out[(r0 + e) * 256 + col] = fmaxf(v, 0.f);
            }
        }
    }
}

extern "C" void kernel_launch(void* const* d_in, const int* in_sizes, int n_in,
                              void* d_out, int out_size, void* d_ws, size_t ws_size,
                              hipStream_t stream) {
    const float* text       = (const float*)d_in[0];
    const float* image      = (const float*)d_in[1];
    const float* W_text     = (const float*)d_in[2];
    const float* b_text     = (const float*)d_in[3];
    const float* W_img      = (const float*)d_in[4];
    const float* b_img      = (const float*)d_in[5];
    const float* in_proj_w  = (const float*)d_in[6];
    const float* in_proj_b  = (const float*)d_in[7];
    const float* out_proj_w = (const float*)d_in[8];
    const float* out_proj_b = (const float*)d_in[9];
    const float* W_fuse     = (const float*)d_in[10];
    const float* b_fuse     = (const float*)d_in[11];
    float* out = (float*)d_out;

    float* ws      = (float*)d_ws;
    float* U0      = ws;                 // 65536
    float* U1      = ws + 65536;         // 65536
    float* Vimg    = ws + 131072;        // 131072
    float* Vtxt    = ws + 262144;        // 131072
    float* vb_img  = ws + 393216;        // 256
    float* vb_txt  = ws + 393472;        // 256
    float* cvec    = ws + 393728;        // 256
    float* b_total = ws + 393984;        // 256
    unsigned short* Wt = (unsigned short*)(ws + 394240);  // 262144 bf16

    k1_tree<<<dim3(97), dim3(512), 0, stream>>>(W_fuse, out_proj_w, in_proj_w, in_proj_b,
                                                W_img, W_text, out_proj_b, b_img, b_text,
                                                U0, U1, Vimg, Vtxt, vb_img, vb_txt, cvec);
    k2_A<<<dim3(65), dim3(512), 0, stream>>>(U0, U1, Vimg, Vtxt, W_fuse, b_fuse,
                                             vb_img, vb_txt, cvec, Wt, b_total);
    fused_gemm<<<dim3(2048), dim3(256), 0, stream>>>(image, text, Wt, b_total, out);
}